// Round 5
// baseline (140.359 us; speedup 1.0000x reference)
//
#include <hip/hip_runtime.h>
#include <hip/hip_bf16.h>
#include <hip/hip_cooperative_groups.h>

namespace cg = cooperative_groups;

typedef __hip_bfloat16 bf16;
typedef __attribute__((ext_vector_type(8))) short short8;
typedef __attribute__((ext_vector_type(4))) float floatx4;

#define DEVI __device__ __forceinline__

DEVI float b2f(bf16 v) { return __bfloat162float(v); }
DEVI bf16 f2b(float v) { return __float2bfloat16(v); }
DEVI unsigned short f2bu(float v) {
    bf16 h = __float2bfloat16(v);
    unsigned short u;
    __builtin_memcpy(&u, &h, 2);
    return u;
}
DEVI float sigmoidf_(float z) { return 1.0f / (1.0f + __expf(-z)); }

// Problem constants
// B=8, H=W=56, C=192, WS=4 -> 14x14 windows, 1568 rows (=98*16), ind=3072,
// hid=ncl=256.  ALL inputs/outputs are float32.
//
// MFMA fragment conventions (mfma_f32_16x16x32_bf16):
//   A[m][k]: lane = quad*16 + m15 -> m = m15, k = quad*8 + j  (16B contiguous)
//   B[k][n]: lane = quad*16 + n15 -> k = quad*8 + j, n = n15
//   D[m][n]: col n = lane&15, row m = quad*4 + reg
//
// Key algebraic identities used:
//   sigmoid(L) > 0.5  <=>  L > 0      (tm literals need only logit signs)
//   clause = AND over included literals of (lit > 0.5)   (min>tau <=> all>tau)
//   feat = sigmoid(clauses @ (vote_w@W2/16) + b2)        (logits not an output)
//
// R5 notes (post-mortems R0->R4):
//   - ~90us of the timed region is harness poison fills (immovable).  All
//     intermediates are L3-resident; kernel work sums to ~20us.  The largest
//     controllable term is LAUNCH STRUCTURE (R4: -7.7us from block migration).
//   - R5: single cooperative kernel, 784 blocks x 256 thr, 3 grid.sync()
//     replacing 3 launch boundaries + 4 dispatch ramps.  Phase bodies are
//     bit-identical copies of the R4 kernels.  Host-side occupancy + launch
//     error checks fall back to the proven R4 4-kernel path.

// ===========================================================================
// Phase bodies as device functions (shared by mega-kernel and fallback).
// ===========================================================================

DEVI void body_repack_frag(const float* __restrict__ W1,
                           unsigned short* __restrict__ w1frag,
                           int fid, int lane) {
    int nb = fid / 96;
    int kb = fid - nb * 96;
    int n = nb * 16 + (lane & 15);
    int k = kb * 32 + (lane >> 4) * 8;
    short8 v;
#pragma unroll
    for (int j = 0; j < 8; j++) {
        v[j] = (short)f2bu(W1[(k + j) * 256 + n]);
    }
    *reinterpret_cast<short8*>(w1frag + ((size_t)fid * 64 + lane) * 8) = v;
}

DEVI void body_mask(const float* __restrict__ inc_w, unsigned* __restrict__ mask,
                    int wi, int t) {
    unsigned bits = 0u;
    int base = t * 512 + wi * 32;
#pragma unroll
    for (int b = 0; b < 32; b++) {
        if (inc_w[base + b] > 0.0f) bits |= (1u << b);
    }
    mask[wi * 256 + t] = bits;
}

DEVI void body_vw2(const float* __restrict__ vote_w, const float* __restrict__ W2,
                   unsigned short* __restrict__ vw2frag, int bid, int t) {
    // vw2 MFMA: M=256(k_out), N=3072, K=192
    int wave = t >> 6;
    int lane = t & 63;
    int quad = lane >> 4;
    int l15 = lane & 15;
    int mt = bid & 15;              // 16-wide k_out tile
    int nt = (bid >> 4) * 4 + wave; // 0..191: 16-wide n tile

    const float* ap = vote_w + (mt * 16 + l15) * 192 + quad * 8;
    const float* bp = W2 + (quad * 8) * 3072 + nt * 16 + l15;

    floatx4 acc = {0.f, 0.f, 0.f, 0.f};
#pragma unroll
    for (int kb = 0; kb < 6; kb++) {
        float4 a0 = *reinterpret_cast<const float4*>(ap + kb * 32);
        float4 a1 = *reinterpret_cast<const float4*>(ap + kb * 32 + 4);
        short8 a, b;
        a[0] = (short)f2bu(a0.x); a[1] = (short)f2bu(a0.y);
        a[2] = (short)f2bu(a0.z); a[3] = (short)f2bu(a0.w);
        a[4] = (short)f2bu(a1.x); a[5] = (short)f2bu(a1.y);
        a[6] = (short)f2bu(a1.z); a[7] = (short)f2bu(a1.w);
#pragma unroll
        for (int j = 0; j < 8; j++) {
            b[j] = (short)f2bu(bp[(kb * 32 + j) * 3072]);
        }
        acc = __builtin_amdgcn_mfma_f32_16x16x32_bf16(a, b, acc, 0, 0, 0);
    }
#pragma unroll
    for (int r = 0; r < 4; r++) {
        int k = mt * 16 + quad * 4 + r;  // gemm2 k index (0..255)
        int off = ((nt * 8 + (k >> 5)) * 64 + ((k >> 3) & 3) * 16 + l15) * 8 + (k & 7);
        vw2frag[off] = f2bu(acc[r] * 0.0625f);  // 1/sqrt(256)
    }
}

// gemm1+LN unit: rows mx*16..+16, k-slice kz (cells {2kz,2kz+1} x 192ch).
// win_s: 16 rows x 384 k (+8 pad) bf16 = 12.5 KB.
DEVI void body_gemm1(const float* __restrict__ x, const float* __restrict__ gamma,
                     const float* __restrict__ beta,
                     const unsigned short* __restrict__ w1frag,
                     float* __restrict__ part,
                     short (*win_s)[392], int mx, int kz, int t) {
    int wave = t >> 6;
    int lane = t & 63;
    int quad = lane >> 4;
    int mlo = lane & 15;
    int m0 = mx * 16;

    // ---- Phase 1: LayerNorm 32 pixels (8 per wave) into LDS ----
    float g0 = gamma[lane], g1 = gamma[lane + 64], g2 = gamma[lane + 128];
    float e0 = beta[lane],  e1 = beta[lane + 64],  e2 = beta[lane + 128];
#pragma unroll
    for (int i = 0; i < 8; i++) {
        int p = wave * 8 + i;          // 0..31
        int lr = p >> 1;               // local row 0..15
        int cell = kz * 2 + (p & 1);   // window cell 0..15
        int row = m0 + lr;
        int b = row / 196;
        int rem = row - b * 196;
        int wh = rem / 14;
        int ww = rem - wh * 14;
        int h_ = wh * 4 + (cell >> 2);
        int w_ = ww * 4 + (cell & 3);
        int hs = h_ + 2; if (hs >= 56) hs -= 56;   // roll(-2,-2) source
        int ws = w_ + 2; if (ws >= 56) ws -= 56;
        const float* xp = x + (((b * 56 + hs) * 56 + ws) * 192);
        float v0 = xp[lane];
        float v1 = xp[lane + 64];
        float v2 = xp[lane + 128];
        float s = v0 + v1 + v2;
        float sq = v0 * v0 + v1 * v1 + v2 * v2;
#pragma unroll
        for (int m = 1; m < 64; m <<= 1) {
            s += __shfl_xor(s, m, 64);
            sq += __shfl_xor(sq, m, 64);
        }
        float mean = s * (1.0f / 192.0f);
        float var = sq * (1.0f / 192.0f) - mean * mean;
        float inv = rsqrtf(var + 1e-5f);
        int kb_ = (p & 1) * 192;       // local k base for this cell
        win_s[lr][kb_ + lane]       = (short)f2bu((v0 - mean) * inv * g0 + e0);
        win_s[lr][kb_ + lane + 64]  = (short)f2bu((v1 - mean) * inv * g1 + e1);
        win_s[lr][kb_ + lane + 128] = (short)f2bu((v2 - mean) * inv * g2 + e2);
    }
    __syncthreads();

    // ---- Phase 2: MFMA.  wave w covers n-tiles [w*4, w*4+4) ----
    int nb0 = wave * 4;
    const unsigned short* bp = w1frag + lane * 8;
    int kb0 = kz * 12;

    floatx4 acc[4];
#pragma unroll
    for (int i = 0; i < 4; i++) acc[i] = (floatx4){0.f, 0.f, 0.f, 0.f};

#pragma unroll 4
    for (int kb = 0; kb < 12; kb++) {
        short8 a = *reinterpret_cast<const short8*>(&win_s[mlo][kb * 32 + quad * 8]);
#pragma unroll
        for (int i = 0; i < 4; i++) {
            short8 b = *reinterpret_cast<const short8*>(
                bp + ((size_t)((nb0 + i) * 96 + kb0 + kb)) * 512);
            acc[i] = __builtin_amdgcn_mfma_f32_16x16x32_bf16(a, b, acc[i], 0, 0, 0);
        }
    }

    float* pp = part + (size_t)kz * 401408;
#pragma unroll
    for (int i = 0; i < 4; i++) {
        int n_g = (nb0 + i) * 16 + mlo;
#pragma unroll
        for (int r = 0; r < 4; r++) {
            int m_g = m0 + quad * 4 + r;
            pp[m_g * 256 + n_g] = acc[i][r];
        }
    }
    __syncthreads();   // win_s reusable by caller's next unit
}

// tm unit: one window row.  g_s: 16 unsigned, red: 4 float (LDS from caller).
DEVI void body_tm(const float* __restrict__ part, const float* __restrict__ b1,
                  const unsigned* __restrict__ mask, float* __restrict__ cl_out,
                  bf16* __restrict__ clauses_bf, float* __restrict__ sum_out,
                  unsigned* g_s, float* red, int row, int t) {
    int wave = t >> 6;
    int lane = t & 63;
    int idx = row * 256 + t;
    float L = b1[t];
#pragma unroll
    for (int s = 0; s < 8; s++) L += part[(size_t)s * 401408 + idx];
    unsigned long long bhi = __ballot(L > 0.0f);  // lit t
    unsigned long long blo = __ballot(L < 0.0f);  // lit 256+t
    if (lane == 0) {
        g_s[wave * 2]         = (unsigned)bhi;
        g_s[wave * 2 + 1]     = (unsigned)(bhi >> 32);
        g_s[8 + wave * 2]     = (unsigned)blo;
        g_s[8 + wave * 2 + 1] = (unsigned)(blo >> 32);
    }
    __syncthreads();
    unsigned ok = 1u;
#pragma unroll
    for (int w = 0; w < 16; w++) {
        unsigned viol = (~g_s[w]) & mask[w * 256 + t];
        ok &= (viol == 0u) ? 1u : 0u;
    }
    float hard = (float)ok;
    cl_out[idx] = hard;
    clauses_bf[idx] = f2b(hard);
    unsigned long long cb = __ballot(ok != 0u);
    if (lane == 0) red[wave] = (float)__popcll(cb);
    __syncthreads();
    if (t == 0) sum_out[row] = (red[0] + red[1] + red[2] + red[3]) * (1.0f / 256.0f);
}

// gemm2 unit: fused feat-sigmoid + window-reverse + roll(+2,+2) + gated
// residual.  Unit (bxx, by): m-tile bxx (32 rows), n-tiles by*8..+8.
DEVI void body_gemm2(const bf16* __restrict__ clauses_bf,
                     const unsigned short* __restrict__ vw2frag,
                     const float* __restrict__ b2v, const float* __restrict__ x,
                     float g, float* __restrict__ out, int bxx, int by, int t) {
    int wave = t >> 6;
    int lane = t & 63;
    int quad = lane >> 4;
    int mlo = lane & 15;
    int wm = wave & 1;
    int wn = wave >> 1;
    int m0 = bxx * 32 + wm * 16;
    int nb0 = by * 8 + wn * 4;  // 16-wide n-tile base (0..191)

    const bf16* ap = clauses_bf + (m0 + mlo) * 256 + quad * 8;
    const unsigned short* bp = vw2frag + lane * 8;

    floatx4 acc[4];
#pragma unroll
    for (int i = 0; i < 4; i++) acc[i] = (floatx4){0.f, 0.f, 0.f, 0.f};

#pragma unroll
    for (int kb = 0; kb < 8; kb++) {
        short8 a = *reinterpret_cast<const short8*>(ap + kb * 32);
#pragma unroll
        for (int i = 0; i < 4; i++) {
            short8 b = *reinterpret_cast<const short8*>(
                bp + ((size_t)((nb0 + i) * 8 + kb)) * 512);
            acc[i] = __builtin_amdgcn_mfma_f32_16x16x32_bf16(a, b, acc[i], 0, 0, 0);
        }
    }

    // per-r inverse window mapping: m_g -> (batch, window-h, window-w)
    int bq[4], wh[4], ww[4];
#pragma unroll
    for (int r = 0; r < 4; r++) {
        int m_g = m0 + quad * 4 + r;
        bq[r] = m_g / 196;
        int rem = m_g - bq[r] * 196;
        wh[r] = rem / 14;
        ww[r] = rem - wh[r] * 14;
    }
#pragma unroll
    for (int i = 0; i < 4; i++) {
        int n_g = (nb0 + i) * 16 + mlo;
        int cell = n_g / 192;           // 0..15 (position inside 4x4 window)
        int ch = n_g - cell * 192;      // channel
        int cellh = cell >> 2;
        int cellw = cell & 3;
        float bb = b2v[n_g];
#pragma unroll
        for (int r = 0; r < 4; r++) {
            int hh = wh[r] * 4 + cellh + 2; if (hh >= 56) hh -= 56;  // roll(+2)
            int wc = ww[r] * 4 + cellw + 2; if (wc >= 56) wc -= 56;
            int gid = ((bq[r] * 56 + hh) * 56 + wc) * 192 + ch;
            float mv = sigmoidf_(acc[i][r] + bb);
            out[gid] = x[gid] + g * mv + (1.0f - g) * sigmoidf_(mv);
        }
    }
}

// ===========================================================================
// Mega-kernel: 784 blocks x 256 threads, cooperative.  4 phases, 3 grid syncs.
//   P0: W1 repack (1536 wave-units) + vw2 (768 block-units) + mask (16)
//   P1: gemm1_ln (784 units, 1:1)
//   P2: tm (1568 units, 2 per block)
//   P3: gemm2 (1176 units, 1.5 per block)
// ===========================================================================
__global__ __launch_bounds__(256, 4) void mega(const float* __restrict__ x,
                                               const float* __restrict__ gamma,
                                               const float* __restrict__ beta,
                                               const float* __restrict__ W1,
                                               const float* __restrict__ b1,
                                               const float* __restrict__ inc_w,
                                               const float* __restrict__ vote_w,
                                               const float* __restrict__ W2,
                                               const float* __restrict__ b2v,
                                               const float* __restrict__ gate,
                                               float* __restrict__ part,
                                               unsigned short* __restrict__ w1frag,
                                               unsigned short* __restrict__ vw2frag,
                                               bf16* __restrict__ clauses_bf,
                                               unsigned* __restrict__ mask,
                                               float* __restrict__ cl_out,
                                               float* __restrict__ sum_out,
                                               float* __restrict__ out) {
    __shared__ short win_s[16][392];   // 12.5 KB; aliased by tm phase
    unsigned* g_s = reinterpret_cast<unsigned*>(&win_s[0][0]);
    float* red = reinterpret_cast<float*>(&win_s[0][0]) + 16;

    cg::grid_group gg = cg::this_grid();
    int bx = blockIdx.x;   // 0..783
    int t = threadIdx.x;
    int wave = t >> 6;
    int lane = t & 63;

    // ---- P0 ----
    {
        int gw = bx * 4 + wave;        // 0..3135
        if (gw < 1536) body_repack_frag(W1, w1frag, gw, lane);
        if (bx >= 768) body_mask(inc_w, mask, bx - 768, t);
        else           body_vw2(vote_w, W2, vw2frag, bx, t);
    }
    __threadfence();
    gg.sync();

    // ---- P1: gemm1 unit bx ----
    {
        int kz = bx / 98;
        int mx = bx - kz * 98;
        body_gemm1(x, gamma, beta, w1frag, part, win_s, mx, kz, t);
    }
    __threadfence();
    gg.sync();

    // ---- P2: tm units bx, bx+784 ----
    body_tm(part, b1, mask, cl_out, clauses_bf, sum_out, g_s, red, bx, t);
    __syncthreads();
    body_tm(part, b1, mask, cl_out, clauses_bf, sum_out, g_s, red, bx + 784, t);
    __threadfence();
    gg.sync();

    // ---- P3: gemm2 units bx (+784 for bx<392) ----
    {
        float g = sigmoidf_(gate[0]);
        int u = bx;
        int by = u / 49;
        int bxx = u - by * 49;
        body_gemm2(clauses_bf, vw2frag, b2v, x, g, out, bxx, by, t);
        if (bx < 392) {
            u = bx + 784;
            by = u / 49;
            bxx = u - by * 49;
            body_gemm2(clauses_bf, vw2frag, b2v, x, g, out, bxx, by, t);
        }
    }
}

// ===========================================================================
// Fallback path: the proven R4 4-kernel pipeline (bit-identical bodies).
// ===========================================================================
__global__ __launch_bounds__(256) void pre_kernel(const float* __restrict__ W1,
                                                  unsigned short* __restrict__ w1frag) {
    body_repack_frag(W1, w1frag, blockIdx.x * 4 + (threadIdx.x >> 6), threadIdx.x & 63);
}

__global__ __launch_bounds__(256) void gemm1_ln(const float* __restrict__ x,
                                                const float* __restrict__ gamma,
                                                const float* __restrict__ beta,
                                                const unsigned short* __restrict__ w1frag,
                                                const float* __restrict__ inc_w,
                                                float* __restrict__ part,
                                                unsigned* __restrict__ mask) {
    __shared__ short win_s[16][392];
    int bx = blockIdx.x;
    int t = threadIdx.x;
    if (bx < 16) {
        body_mask(inc_w, mask, bx, t);
        return;
    }
    int g = bx - 16;
    int kz = g / 98;
    int mx = g - kz * 98;
    body_gemm1(x, gamma, beta, w1frag, part, win_s, mx, kz, t);
}

__global__ __launch_bounds__(256) void tm_vw2(const float* __restrict__ part,
                                              const float* __restrict__ b1,
                                              const unsigned* __restrict__ mask,
                                              const float* __restrict__ vote_w,
                                              const float* __restrict__ W2,
                                              unsigned short* __restrict__ vw2frag,
                                              float* __restrict__ cl_out,
                                              bf16* __restrict__ clauses_bf,
                                              float* __restrict__ sum_out) {
    __shared__ unsigned g_s[16];
    __shared__ float red[4];
    int bx = blockIdx.x;
    int t = threadIdx.x;
    if (bx < 768) {
        body_vw2(vote_w, W2, vw2frag, bx, t);
        return;
    }
    body_tm(part, b1, mask, cl_out, clauses_bf, sum_out, g_s, red, bx - 768, t);
}

__global__ __launch_bounds__(256) void gemm2_out(const bf16* __restrict__ clauses_bf,
                                                 const unsigned short* __restrict__ vw2frag,
                                                 const float* __restrict__ b2v,
                                                 const float* __restrict__ x,
                                                 const float* __restrict__ gate,
                                                 float* __restrict__ out) {
    float g = sigmoidf_(gate[0]);
    body_gemm2(clauses_bf, vw2frag, b2v, x, g, out, blockIdx.x, blockIdx.y, threadIdx.x);
}

// ---------------------------------------------------------------------------
extern "C" void kernel_launch(void* const* d_in, const int* in_sizes, int n_in,
                              void* d_out, int out_size, void* d_ws, size_t ws_size,
                              hipStream_t stream) {
    const float* x      = (const float*)d_in[0];
    const float* gamma  = (const float*)d_in[1];
    const float* beta   = (const float*)d_in[2];
    const float* W1     = (const float*)d_in[3];
    const float* b1     = (const float*)d_in[4];
    const float* inc_w  = (const float*)d_in[5];
    const float* vote_w = (const float*)d_in[6];
    const float* W2     = (const float*)d_in[7];
    const float* b2v    = (const float*)d_in[8];
    const float* gate   = (const float*)d_in[9];

    char* ws = (char*)d_ws;
    // workspace carve (bytes), total ~16.8 MB:
    float*          part       = (float*)(ws + 0);                 // 12,845,056 (8x 1568*256*4)
    unsigned short* w1frag     = (unsigned short*)(ws + 12845056); // 1,572,864
    unsigned short* vw2frag    = (unsigned short*)(ws + 14417920); // 1,572,864
    bf16*           clauses_bf = (bf16*)(ws + 15990784);           //   802,816
    unsigned*       mask       = (unsigned*)(ws + 16793600);       //    16,384

    float* out     = (float*)d_out;
    float* cl_out  = out + 4816896;            // clauses: 1568*256
    float* sum_out = cl_out + 401408;          // summary: 1568

    // Cooperative capacity check (host-side, capture-time only; no allocs).
    bool coop_ok = false;
    {
        int maxb = 0;
        hipError_t e = hipOccupancyMaxActiveBlocksPerMultiprocessor(
            &maxb, (const void*)mega, 256, 0);
        if (e == hipSuccess && maxb * 256 >= 784) coop_ok = true;
        else (void)hipGetLastError();
    }

    if (coop_ok) {
        void* args[] = {(void*)&x, (void*)&gamma, (void*)&beta, (void*)&W1,
                        (void*)&b1, (void*)&inc_w, (void*)&vote_w, (void*)&W2,
                        (void*)&b2v, (void*)&gate, (void*)&part, (void*)&w1frag,
                        (void*)&vw2frag, (void*)&clauses_bf, (void*)&mask,
                        (void*)&cl_out, (void*)&sum_out, (void*)&out};
        hipError_t e = hipLaunchCooperativeKernel((const void*)mega, dim3(784),
                                                  dim3(256), args, 0, stream);
        if (e == hipSuccess) return;
        (void)hipGetLastError();   // clear and fall through to fallback
    }

    // Fallback: proven R4 pipeline.
    pre_kernel<<<384, 256, 0, stream>>>(W1, w1frag);
    gemm1_ln<<<800, 256, 0, stream>>>(x, gamma, beta, w1frag, inc_w, part, mask);
    tm_vw2<<<2336, 256, 0, stream>>>(part, b1, mask, vote_w, W2, vw2frag,
                                     cl_out, clauses_bf, sum_out);
    gemm2_out<<<dim3(49, 24), 256, 0, stream>>>(clauses_bf, vw2frag, b2v, x, gate, out);
}

// Round 6
// 133.104 us; speedup vs baseline: 1.0545x; 1.0545x over previous
//
#include <hip/hip_runtime.h>
#include <hip/hip_bf16.h>

typedef __hip_bfloat16 bf16;
typedef __attribute__((ext_vector_type(8))) short short8;
typedef __attribute__((ext_vector_type(4))) float floatx4;

#define DEVI __device__ __forceinline__

DEVI float b2f(bf16 v) { return __bfloat162float(v); }
DEVI bf16 f2b(float v) { return __float2bfloat16(v); }
DEVI unsigned short f2bu(float v) {
    bf16 h = __float2bfloat16(v);
    unsigned short u;
    __builtin_memcpy(&u, &h, 2);
    return u;
}
DEVI float sigmoidf_(float z) { return 1.0f / (1.0f + __expf(-z)); }

// Problem constants
// B=8, H=W=56, C=192, WS=4 -> 14x14 windows, 1568 rows (=98*16), ind=3072,
// hid=ncl=256.  ALL inputs/outputs are float32.
//
// MFMA fragment conventions (mfma_f32_16x16x32_bf16):
//   A[m][k]: lane = quad*16 + m15 -> m = m15, k = quad*8 + j  (16B contiguous)
//   B[k][n]: lane = quad*16 + n15 -> k = quad*8 + j, n = n15
//   D[m][n]: col n = lane&15, row m = quad*4 + reg
//
// Key algebraic identities used:
//   sigmoid(L) > 0.5  <=>  L > 0      (tm literals need only logit signs)
//   clause = AND over included literals of (lit > 0.5)   (min>tau <=> all>tau)
//   feat = sigmoid(clauses @ (vote_w@W2/16) + b2)        (logits not an output)
//
// R6 notes (post-mortems R0->R5):
//   - ~90us of the timed region is harness poison fills (immovable).  All
//     intermediates are L3-resident; byte-saving on them is worthless.
//     gemm2 has a ~6us true-HBM floor (x read + out write).
//   - R1 (98-block fusion) / R2 (392-block gemm1) lost occupancy: keep GEMM
//     grids >= ~784 blocks.
//   - R3 (LN inlined into gemm1, win deleted): neutral on time, kept for
//     simplicity.  R4 (block migration across launch boundaries): -7.7us,
//     the one structural win (133.66us).
//   - R5 (cooperative mega-kernel, 3 grid.sync): mega ran 527us -- on 8-XCD
//     CDNA4 a grid.sync (cross-XCD atomic rendezvous + threadfence flush)
//     costs far more than the ~2us launch boundary it replaces.  REVERTED.
//   - R6 = exact R4 configuration (proven 133.66us).  Structure:
//       L1 pre    (384):  W1 repack only -- the sole L2 dependency;
//       L2 gemm1  (800):  16 mask blocks + 784 LN+GEMM blocks;
//       L3 tm_vw2 (2336): 768 vw2 blocks (consumed at L4) + 1568 tm rows;
//       L4 gemm2  (49x24): fused epilogue.

// ---------------------------------------------------------------------------
// L1: W1 f32 -> bf16 B-fragment repack.  One 1KB fragment per wave,
// coalesced 16B/lane stores.  384 blocks.
__global__ __launch_bounds__(256) void pre_kernel(const float* __restrict__ W1,
                                                  unsigned short* __restrict__ w1frag) {
    int bid = blockIdx.x;          // 0..383
    int t = threadIdx.x;
    int lane = t & 63;
    int fid = bid * 4 + (t >> 6);  // = nb*96 + kb
    int nb = fid / 96;
    int kb = fid - nb * 96;
    int n = nb * 16 + (lane & 15);
    int k = kb * 32 + (lane >> 4) * 8;
    short8 v;
#pragma unroll
    for (int j = 0; j < 8; j++) {
        v[j] = (short)f2bu(W1[(k + j) * 256 + n]);
    }
    *reinterpret_cast<short8*>(w1frag + ((size_t)fid * 64 + lane) * 8) = v;
}

// ---------------------------------------------------------------------------
// L2: fused LN + raw logit partials of win @ W1 (+ 16 inc-bitmask blocks in
// dispatch round 0).  M=1568, N=256, K=3072, 8-way K-split.
// Gemm blocks: (98 m x 8 kz) = 784 (12 waves/CU), 4 waves.
// Block (mx,kz): rows mx*16..+16, k in [kz*384,+384) = window cells
// {2kz,2kz+1} x 192ch = 32 source pixels.  Phase 1: each wave LNs 8 pixels
// from x (roll(-2,-2) + window partition via index math) into LDS.
// Phase 2: A-fragments from LDS (pad-392 -> 2-way banks = free), B from
// w1frag, 4 acc tiles/wave, f32 partials (R0-proven tm path, bit-identical).
__global__ __launch_bounds__(256) void gemm1_ln(const float* __restrict__ x,
                                                const float* __restrict__ gamma,
                                                const float* __restrict__ beta,
                                                const unsigned short* __restrict__ w1frag,
                                                const float* __restrict__ inc_w,
                                                float* __restrict__ part,
                                                unsigned* __restrict__ mask) {
    __shared__ short win_s[16][392];   // 16 rows x 384 k (+8 pad) bf16 = 12.5 KB
    int bx = blockIdx.x;
    int t = threadIdx.x;
    if (bx < 16) {
        // ---- inc bitmask (round-0 blocks; consumed by L3) ----
        int wi = bx;                   // 0..15
        unsigned bits = 0u;
        int base = t * 512 + wi * 32;
#pragma unroll
        for (int b = 0; b < 32; b++) {
            if (inc_w[base + b] > 0.0f) bits |= (1u << b);
        }
        mask[wi * 256 + t] = bits;
        return;
    }
    int g = bx - 16;                   // 0..783
    int kz = g / 98;                   // 0..7
    int mx = g - kz * 98;              // 0..97
    int wave = t >> 6;
    int lane = t & 63;
    int quad = lane >> 4;
    int mlo = lane & 15;
    int m0 = mx * 16;

    // ---- Phase 1: LayerNorm 32 pixels (8 per wave) into LDS ----
    float g0 = gamma[lane], g1 = gamma[lane + 64], g2 = gamma[lane + 128];
    float e0 = beta[lane],  e1 = beta[lane + 64],  e2 = beta[lane + 128];
#pragma unroll
    for (int i = 0; i < 8; i++) {
        int p = wave * 8 + i;          // 0..31
        int lr = p >> 1;               // local row 0..15
        int cell = kz * 2 + (p & 1);   // window cell 0..15
        int row = m0 + lr;
        int b = row / 196;
        int rem = row - b * 196;
        int wh = rem / 14;
        int ww = rem - wh * 14;
        int h_ = wh * 4 + (cell >> 2);
        int w_ = ww * 4 + (cell & 3);
        int hs = h_ + 2; if (hs >= 56) hs -= 56;   // roll(-2,-2) source
        int ws = w_ + 2; if (ws >= 56) ws -= 56;
        const float* xp = x + (((b * 56 + hs) * 56 + ws) * 192);
        float v0 = xp[lane];
        float v1 = xp[lane + 64];
        float v2 = xp[lane + 128];
        float s = v0 + v1 + v2;
        float sq = v0 * v0 + v1 * v1 + v2 * v2;
#pragma unroll
        for (int m = 1; m < 64; m <<= 1) {
            s += __shfl_xor(s, m, 64);
            sq += __shfl_xor(sq, m, 64);
        }
        float mean = s * (1.0f / 192.0f);
        float var = sq * (1.0f / 192.0f) - mean * mean;
        float inv = rsqrtf(var + 1e-5f);
        int kb_ = (p & 1) * 192;       // local k base for this cell
        win_s[lr][kb_ + lane]       = (short)f2bu((v0 - mean) * inv * g0 + e0);
        win_s[lr][kb_ + lane + 64]  = (short)f2bu((v1 - mean) * inv * g1 + e1);
        win_s[lr][kb_ + lane + 128] = (short)f2bu((v2 - mean) * inv * g2 + e2);
    }
    __syncthreads();

    // ---- Phase 2: MFMA.  wave w covers n-tiles [w*4, w*4+4) ----
    int nb0 = wave * 4;
    const unsigned short* bp = w1frag + lane * 8;
    int kb0 = kz * 12;

    floatx4 acc[4];
#pragma unroll
    for (int i = 0; i < 4; i++) acc[i] = (floatx4){0.f, 0.f, 0.f, 0.f};

#pragma unroll 4
    for (int kb = 0; kb < 12; kb++) {
        short8 a = *reinterpret_cast<const short8*>(&win_s[mlo][kb * 32 + quad * 8]);
#pragma unroll
        for (int i = 0; i < 4; i++) {
            short8 b = *reinterpret_cast<const short8*>(
                bp + ((size_t)((nb0 + i) * 96 + kb0 + kb)) * 512);
            acc[i] = __builtin_amdgcn_mfma_f32_16x16x32_bf16(a, b, acc[i], 0, 0, 0);
        }
    }

    float* pp = part + (size_t)kz * 401408;
#pragma unroll
    for (int i = 0; i < 4; i++) {
        int n_g = (nb0 + i) * 16 + mlo;
#pragma unroll
        for (int r = 0; r < 4; r++) {
            int m_g = m0 + quad * 4 + r;
            pp[m_g * 256 + n_g] = acc[i][r];
        }
    }
}

// ---------------------------------------------------------------------------
// L3: [0,768) vw2 = vote_w @ W2 / 16 via MFMA -> vw2frag (consumed by L4);
//     [768, 2336) clauses via bitwise AND over logit signs (1 block/row).
// lit t included-true  <=> logit > 0;  lit 256+t  <=> logit < 0.
__global__ __launch_bounds__(256) void tm_vw2(const float* __restrict__ part,
                                              const float* __restrict__ b1,
                                              const unsigned* __restrict__ mask,
                                              const float* __restrict__ vote_w,
                                              const float* __restrict__ W2,
                                              unsigned short* __restrict__ vw2frag,
                                              float* __restrict__ cl_out,
                                              bf16* __restrict__ clauses_bf,
                                              float* __restrict__ sum_out) {
    __shared__ unsigned g_s[16];
    __shared__ float red[4];
    int bx = blockIdx.x;
    int t = threadIdx.x;
    int wave = t >> 6;
    int lane = t & 63;
    if (bx < 768) {
        // ---- vw2 MFMA: M=256(k_out), N=3072, K=192 ----
        int bid = bx;                  // 0..767
        int quad = lane >> 4;
        int l15 = lane & 15;
        int mt = bid & 15;             // 16-wide k_out tile
        int nt = (bid >> 4) * 4 + wave; // 0..191: 16-wide n tile

        const float* ap = vote_w + (mt * 16 + l15) * 192 + quad * 8;
        const float* bp = W2 + (quad * 8) * 3072 + nt * 16 + l15;

        floatx4 acc = {0.f, 0.f, 0.f, 0.f};
#pragma unroll
        for (int kb = 0; kb < 6; kb++) {
            float4 a0 = *reinterpret_cast<const float4*>(ap + kb * 32);
            float4 a1 = *reinterpret_cast<const float4*>(ap + kb * 32 + 4);
            short8 a, b;
            a[0] = (short)f2bu(a0.x); a[1] = (short)f2bu(a0.y);
            a[2] = (short)f2bu(a0.z); a[3] = (short)f2bu(a0.w);
            a[4] = (short)f2bu(a1.x); a[5] = (short)f2bu(a1.y);
            a[6] = (short)f2bu(a1.z); a[7] = (short)f2bu(a1.w);
#pragma unroll
            for (int j = 0; j < 8; j++) {
                b[j] = (short)f2bu(bp[(kb * 32 + j) * 3072]);
            }
            acc = __builtin_amdgcn_mfma_f32_16x16x32_bf16(a, b, acc, 0, 0, 0);
        }
#pragma unroll
        for (int r = 0; r < 4; r++) {
            int k = mt * 16 + quad * 4 + r;  // gemm2 k index (0..255)
            int off = ((nt * 8 + (k >> 5)) * 64 + ((k >> 3) & 3) * 16 + l15) * 8 + (k & 7);
            vw2frag[off] = f2bu(acc[r] * 0.0625f);  // 1/sqrt(256)
        }
        return;
    }
    // ---- tm: one block per window row ----
    int row = bx - 768;
    int idx = row * 256 + t;
    float L = b1[t];
#pragma unroll
    for (int s = 0; s < 8; s++) L += part[(size_t)s * 401408 + idx];
    unsigned long long bhi = __ballot(L > 0.0f);  // lit t
    unsigned long long blo = __ballot(L < 0.0f);  // lit 256+t
    if (lane == 0) {
        g_s[wave * 2]         = (unsigned)bhi;
        g_s[wave * 2 + 1]     = (unsigned)(bhi >> 32);
        g_s[8 + wave * 2]     = (unsigned)blo;
        g_s[8 + wave * 2 + 1] = (unsigned)(blo >> 32);
    }
    __syncthreads();
    unsigned ok = 1u;
#pragma unroll
    for (int w = 0; w < 16; w++) {
        unsigned viol = (~g_s[w]) & mask[w * 256 + t];
        ok &= (viol == 0u) ? 1u : 0u;
    }
    float hard = (float)ok;
    cl_out[idx] = hard;
    clauses_bf[idx] = f2b(hard);
    unsigned long long cb = __ballot(ok != 0u);
    if (lane == 0) red[wave] = (float)__popcll(cb);
    __syncthreads();
    if (t == 0) sum_out[row] = (red[0] + red[1] + red[2] + red[3]) * (1.0f / 256.0f);
}

// ---------------------------------------------------------------------------
// L4: fused  feat = sigmoid(clauses @ vw2 + b2)  +  window-reverse + roll(+2,+2)
// + gated residual -> out.  M=1568, N=3072, K=256.  grid (49, 24), 4 waves
// 2m x 2n, wave tile 16m x 64n (4 acc tiles).  feat never materialized.
__global__ __launch_bounds__(256) void gemm2_out(const bf16* __restrict__ clauses_bf,
                                                 const unsigned short* __restrict__ vw2frag,
                                                 const float* __restrict__ b2v,
                                                 const float* __restrict__ x,
                                                 const float* __restrict__ gate,
                                                 float* __restrict__ out) {
    int t = threadIdx.x;
    int wave = t >> 6;
    int lane = t & 63;
    int quad = lane >> 4;
    int mlo = lane & 15;
    int wm = wave & 1;
    int wn = wave >> 1;
    int m0 = blockIdx.x * 32 + wm * 16;
    int nb0 = blockIdx.y * 8 + wn * 4;  // 16-wide n-tile base (0..191)

    const bf16* ap = clauses_bf + (m0 + mlo) * 256 + quad * 8;
    const unsigned short* bp = vw2frag + lane * 8;

    floatx4 acc[4];
#pragma unroll
    for (int i = 0; i < 4; i++) acc[i] = (floatx4){0.f, 0.f, 0.f, 0.f};

#pragma unroll
    for (int kb = 0; kb < 8; kb++) {
        short8 a = *reinterpret_cast<const short8*>(ap + kb * 32);
#pragma unroll
        for (int i = 0; i < 4; i++) {
            short8 b = *reinterpret_cast<const short8*>(
                bp + ((size_t)((nb0 + i) * 8 + kb)) * 512);
            acc[i] = __builtin_amdgcn_mfma_f32_16x16x32_bf16(a, b, acc[i], 0, 0, 0);
        }
    }

    float g = sigmoidf_(gate[0]);
    // per-r inverse window mapping: m_g -> (batch, window-h, window-w)
    int bq[4], wh[4], ww[4];
#pragma unroll
    for (int r = 0; r < 4; r++) {
        int m_g = m0 + quad * 4 + r;
        bq[r] = m_g / 196;
        int rem = m_g - bq[r] * 196;
        wh[r] = rem / 14;
        ww[r] = rem - wh[r] * 14;
    }
#pragma unroll
    for (int i = 0; i < 4; i++) {
        int n_g = (nb0 + i) * 16 + mlo;
        int cell = n_g / 192;           // 0..15 (position inside 4x4 window)
        int ch = n_g - cell * 192;      // channel
        int cellh = cell >> 2;
        int cellw = cell & 3;
        float bb = b2v[n_g];
#pragma unroll
        for (int r = 0; r < 4; r++) {
            int hh = wh[r] * 4 + cellh + 2; if (hh >= 56) hh -= 56;  // roll(+2)
            int wc = ww[r] * 4 + cellw + 2; if (wc >= 56) wc -= 56;
            int gid = ((bq[r] * 56 + hh) * 56 + wc) * 192 + ch;
            float mv = sigmoidf_(acc[i][r] + bb);
            out[gid] = x[gid] + g * mv + (1.0f - g) * sigmoidf_(mv);
        }
    }
}

// ---------------------------------------------------------------------------
extern "C" void kernel_launch(void* const* d_in, const int* in_sizes, int n_in,
                              void* d_out, int out_size, void* d_ws, size_t ws_size,
                              hipStream_t stream) {
    const float* x      = (const float*)d_in[0];
    const float* gamma  = (const float*)d_in[1];
    const float* beta   = (const float*)d_in[2];
    const float* W1     = (const float*)d_in[3];
    const float* b1     = (const float*)d_in[4];
    const float* inc_w  = (const float*)d_in[5];
    const float* vote_w = (const float*)d_in[6];
    const float* W2     = (const float*)d_in[7];
    const float* b2v    = (const float*)d_in[8];
    const float* gate   = (const float*)d_in[9];

    char* ws = (char*)d_ws;
    // workspace carve (bytes), total ~16.8 MB:
    float*          part       = (float*)(ws + 0);                 // 12,845,056 (8x 1568*256*4)
    unsigned short* w1frag     = (unsigned short*)(ws + 12845056); // 1,572,864
    unsigned short* vw2frag    = (unsigned short*)(ws + 14417920); // 1,572,864
    bf16*           clauses_bf = (bf16*)(ws + 15990784);           //   802,816
    unsigned*       mask       = (unsigned*)(ws + 16793600);       //    16,384

    float* out     = (float*)d_out;
    float* cl_out  = out + 4816896;            // clauses: 1568*256
    float* sum_out = cl_out + 401408;          // summary: 1568

    pre_kernel<<<384, 256, 0, stream>>>(W1, w1frag);
    gemm1_ln<<<800, 256, 0, stream>>>(x, gamma, beta, w1frag, inc_w, part, mask);
    tm_vw2<<<2336, 256, 0, stream>>>(part, b1, mask, vote_w, W2, vw2frag,
                                     cl_out, clauses_bf, sum_out);
    gemm2_out<<<dim3(49, 24), 256, 0, stream>>>(clauses_bf, vw2frag, b2v, x, gate, out);
}